// Round 1
// baseline (596.636 us; speedup 1.0000x reference)
//
#include <hip/hip_runtime.h>
#include <stdint.h>

// CSENet: per-pixel argmin over 27554 vertex embeddings (16-dim, fp32).
// dist = |x|^2 - 2 x.w + |w|^2 ; argmin(dist) == argmin(0.5|w|^2 - x.w).
// Score m = h + sum(-w[k] * x[k]) with h = 0.5*|w|^2  -> pure FMA chain.
// Cross-chunk reduction via u64 atomicMin on (sortable_f32(m) << 32 | idx):
// smaller m wins, tie -> smaller idx == np.argmin first-occurrence.

#define DIMS   16
#define HW     12544          // 112*112
#define P_TOT  50176          // 4*112*112
#define V_TOT  27554
#define FEAT_N 802816         // 4*16*112*112
#define NV     64             // vertex chunks
#define VC     431            // ceil(27554/64)
#define PPT    4              // pixels per thread (float4 along W)

__global__ __launch_bounds__(256, 2)
void cse_argmin(const float* __restrict__ feats,
                const float* __restrict__ ve,
                unsigned long long* __restrict__ keys)
{
    __shared__ float4 se4[VC * 4];   // negated vertex embeddings, 4 float4 each
    __shared__ float  sh[VC];        // h = 0.5*|w|^2

    const int j   = blockIdx.y;
    const int v0  = j * VC;
    const int cnt = min(VC, V_TOT - v0);

    // ---- stage chunk into LDS (negated) + compute h ----
    for (int t = threadIdx.x; t < cnt; t += 256) {
        const float4* w4 = (const float4*)(ve + (size_t)(v0 + t) * DIMS);
        float4 a = w4[0], b = w4[1], c = w4[2], d = w4[3];
        float h = a.x*a.x + a.y*a.y + a.z*a.z + a.w*a.w
                + b.x*b.x + b.y*b.y + b.z*b.z + b.w*b.w
                + c.x*c.x + c.y*c.y + c.z*c.z + c.w*c.w
                + d.x*d.x + d.y*d.y + d.z*d.z + d.w*d.w;
        se4[t*4+0] = make_float4(-a.x, -a.y, -a.z, -a.w);
        se4[t*4+1] = make_float4(-b.x, -b.y, -b.z, -b.w);
        se4[t*4+2] = make_float4(-c.x, -c.y, -c.z, -c.w);
        se4[t*4+3] = make_float4(-d.x, -d.y, -d.z, -d.w);
        sh[t] = 0.5f * h;
    }
    __syncthreads();

    // ---- load 4 consecutive pixels' 16-dim embeddings ----
    const int p0 = (blockIdx.x * 256 + threadIdx.x) * PPT;
    const int bb = p0 / HW;
    const int hw = p0 - bb * HW;
    const float* fb = feats + (size_t)bb * (DIMS * HW) + hw;
    float4 x[DIMS];
#pragma unroll
    for (int d = 0; d < DIMS; ++d)
        x[d] = *(const float4*)(fb + d * HW);

    float m0b = 3.4e38f, m1b = 3.4e38f, m2b = 3.4e38f, m3b = 3.4e38f;
    int   i0 = 0, i1 = 0, i2 = 0, i3 = 0;

#pragma unroll 2
    for (int v = 0; v < cnt; ++v) {
        const float h = sh[v];
        float m0 = h, m1 = h, m2 = h, m3 = h;
#pragma unroll
        for (int k = 0; k < 4; ++k) {
            const float4 nw = se4[v*4 + k];                 // uniform broadcast read
            const float4 xa = x[4*k+0], xb = x[4*k+1], xc = x[4*k+2], xd = x[4*k+3];
            m0 = fmaf(nw.x, xa.x, m0); m0 = fmaf(nw.y, xb.x, m0);
            m0 = fmaf(nw.z, xc.x, m0); m0 = fmaf(nw.w, xd.x, m0);
            m1 = fmaf(nw.x, xa.y, m1); m1 = fmaf(nw.y, xb.y, m1);
            m1 = fmaf(nw.z, xc.y, m1); m1 = fmaf(nw.w, xd.y, m1);
            m2 = fmaf(nw.x, xa.z, m2); m2 = fmaf(nw.y, xb.z, m2);
            m2 = fmaf(nw.z, xc.z, m2); m2 = fmaf(nw.w, xd.z, m2);
            m3 = fmaf(nw.x, xa.w, m3); m3 = fmaf(nw.y, xb.w, m3);
            m3 = fmaf(nw.z, xc.w, m3); m3 = fmaf(nw.w, xd.w, m3);
        }
        const int vg = v0 + v;
        bool c0 = m0 < m0b; m0b = c0 ? m0 : m0b; i0 = c0 ? vg : i0;
        bool c1 = m1 < m1b; m1b = c1 ? m1 : m1b; i1 = c1 ? vg : i1;
        bool c2 = m2 < m2b; m2b = c2 ? m2 : m2b; i2 = c2 ? vg : i2;
        bool c3 = m3 < m3b; m3b = c3 ? m3 : m3b; i3 = c3 ? vg : i3;
    }

    // ---- pack (sortable score, idx) and atomically min-reduce ----
    unsigned long long* kp = keys + p0;
    float  mb[PPT] = { m0b, m1b, m2b, m3b };
    int    ib[PPT] = { i0, i1, i2, i3 };
#pragma unroll
    for (int p = 0; p < PPT; ++p) {
        unsigned s = __float_as_uint(mb[p]);
        s = (s & 0x80000000u) ? ~s : (s | 0x80000000u);   // order-preserving map
        unsigned long long key = ((unsigned long long)s << 32) | (unsigned)ib[p];
        atomicMin(&kp[p], key);
    }
}

__global__ void cse_finalize(const unsigned long long* __restrict__ keys,
                             float* __restrict__ out)
{
    int p = blockIdx.x * 256 + threadIdx.x;
    if (p < P_TOT)
        out[FEAT_N + p] = (float)(unsigned)(keys[p] & 0xffffffffull);
}

extern "C" void kernel_launch(void* const* d_in, const int* in_sizes, int n_in,
                              void* d_out, int out_size, void* d_ws, size_t ws_size,
                              hipStream_t stream)
{
    const float* feats = (const float*)d_in[0];
    const float* ve    = (const float*)d_in[1];
    float* out = (float*)d_out;
    unsigned long long* keys = (unsigned long long*)d_ws;

    // init argmin keys to +inf
    hipMemsetAsync(d_ws, 0xFF, (size_t)P_TOT * sizeof(unsigned long long), stream);
    // output 0: feats passthrough
    hipMemcpyAsync(out, feats, (size_t)FEAT_N * sizeof(float),
                   hipMemcpyDeviceToDevice, stream);

    dim3 grid(P_TOT / (256 * PPT), NV);   // 49 x 64
    cse_argmin<<<grid, 256, 0, stream>>>(feats, ve, keys);
    cse_finalize<<<(P_TOT + 255) / 256, 256, 0, stream>>>(keys, out);
}

// Round 2
// 396.294 us; speedup vs baseline: 1.5055x; 1.5055x over previous
//
#include <hip/hip_runtime.h>
#include <stdint.h>

// CSENet: per-pixel argmin over 27554 vertex embeddings (16-dim, fp32).
// Two-stage: (A) bf16 MFMA approx scores s~ = c2 - 2 x.w (c2 folded into K
// slots as bf16 hi+lo), min-only reduction to a per-(pixel,chunk) table.
// (B) exact fp32 refine over candidate chunks selected by a provable bf16
// rounding margin (Cauchy-Schwarz): m_p = 0.004*|x~|*max|w~| + 1e-3.
// Final argmin via packed u64 atomicMin (tie -> smaller index, np semantics).

#define DIMS   16
#define HW     12544
#define P_TOT  50176
#define V_TOT  27554
#define FEAT_N 802816

// MFMA path
#define CV     512            // vertices per chunk
#define NCH    54             // ceil(27554/512)
#define VPAD   (NCH*CV)       // 27648
#define PIXW   128            // pixels per wave
#define TPW    8              // 16-pixel MFMA tiles per wave

// fallback (round-1) path
#define NV     64
#define VC     431
#define PPT    4

typedef __attribute__((ext_vector_type(8))) short bf16x8;
typedef __attribute__((ext_vector_type(4))) float f32x4;

// ws layout (bytes)
#define OFF_KEYS  0ul
#define OFF_N2MAX 401408ul
#define OFF_C2    405504ul      // 27554 f32
#define OFF_XN    516096ul      // 50176 f32
#define OFF_XB    716800ul      // 4*50176*8 shorts (3,211,264 B)
#define OFF_WB    3928064ul     // 54*4*512*8 shorts (1,769,472 B)
#define OFF_CM    5697536ul     // 54*50176 f32 (10,838,016 B)
#define WS_NEED   16535552ul

__device__ __forceinline__ unsigned short rne_bf16(float f) {
    unsigned u = __float_as_uint(f);
    return (unsigned short)((u + 0x7FFFu + ((u >> 16) & 1u)) >> 16);
}
__device__ __forceinline__ float bf2f(unsigned short h) {
    return __uint_as_float(((unsigned)h) << 16);
}
__device__ __forceinline__ unsigned sortable(float s) {
    unsigned u = __float_as_uint(s);
    return (u & 0x80000000u) ? ~u : (u | 0x80000000u);
}

// ---------------- prep: vertices -> bf16 A-fragments + c2 + max|w~|^2 -----
__global__ void prep_v(const float* __restrict__ ve, short* __restrict__ wb,
                       float* __restrict__ c2buf, unsigned* __restrict__ n2max)
{
    int v = blockIdx.x * 256 + threadIdx.x;
    if (v >= VPAD) return;
    int c = v / CV, vl = v % CV;
    bf16x8 r0, r1, r2, r3;
#pragma unroll
    for (int k = 0; k < 8; ++k) { r2[k] = 0; r3[k] = 0; }
    if (v < V_TOT) {
        const float4* w4 = (const float4*)(ve + (size_t)v * DIMS);
        float w[16];
        *(float4*)&w[0] = w4[0]; *(float4*)&w[4]  = w4[1];
        *(float4*)&w[8] = w4[2]; *(float4*)&w[12] = w4[3];
        float c2 = 0.f;
#pragma unroll
        for (int k = 0; k < 16; ++k) c2 = fmaf(w[k], w[k], c2);
        c2buf[v] = c2;
        float n2 = 0.f;
#pragma unroll
        for (int k = 0; k < 16; ++k) {
            unsigned short h = rne_bf16(-2.f * w[k]);
            if (k < 8) r0[k] = (short)h; else r1[k - 8] = (short)h;
            float f = bf2f(h);
            n2 = fmaf(f, f, n2);
        }
        atomicMax(n2max, __float_as_uint(n2));
        unsigned short hi = rne_bf16(c2);
        unsigned short lo = rne_bf16(c2 - bf2f(hi));
        r2[0] = (short)hi; r2[1] = (short)lo;
    } else {
#pragma unroll
        for (int k = 0; k < 8; ++k) { r0[k] = 0; r1[k] = 0; }
        r2[0] = (short)rne_bf16(30000.f);   // padding: huge score, never wins
    }
    *(bf16x8*)(wb + (((size_t)c * 4 + 0) * CV + vl) * 8) = r0;
    *(bf16x8*)(wb + (((size_t)c * 4 + 1) * CV + vl) * 8) = r1;
    *(bf16x8*)(wb + (((size_t)c * 4 + 2) * CV + vl) * 8) = r2;
    *(bf16x8*)(wb + (((size_t)c * 4 + 3) * CV + vl) * 8) = r3;
}

// ---------------- prep: pixels -> bf16 B-fragments + |x~| ------------------
__global__ void prep_x(const float* __restrict__ feats, short* __restrict__ xb,
                       float* __restrict__ xn)
{
    int p = blockIdx.x * 256 + threadIdx.x;     // grid exactly covers 50176
    int b = p / HW, hw = p - b * HW;
    const float* f = feats + (size_t)b * DIMS * HW + hw;
    bf16x8 r0, r1, r2, r3;
#pragma unroll
    for (int k = 0; k < 8; ++k) { r2[k] = 0; r3[k] = 0; }
    float n2 = 0.f;
#pragma unroll
    for (int k = 0; k < 16; ++k) {
        unsigned short h = rne_bf16(f[k * HW]);
        if (k < 8) r0[k] = (short)h; else r1[k - 8] = (short)h;
        float x = bf2f(h);
        n2 = fmaf(x, x, n2);
    }
    r2[0] = (short)0x3F80; r2[1] = (short)0x3F80;   // 1.0, 1.0 (c2 hi+lo slots)
    xn[p] = sqrtf(n2);
    *(bf16x8*)(xb + ((size_t)0 * P_TOT + p) * 8) = r0;
    *(bf16x8*)(xb + ((size_t)1 * P_TOT + p) * 8) = r1;
    *(bf16x8*)(xb + ((size_t)2 * P_TOT + p) * 8) = r2;
    *(bf16x8*)(xb + ((size_t)3 * P_TOT + p) * 8) = r3;
}

// ---------------- pass A: MFMA approx, per-(pixel,chunk) min ---------------
__global__ __launch_bounds__(256)
void pass_a(const short* __restrict__ xb, const short* __restrict__ wb,
            float* __restrict__ chunkmin)
{
    __shared__ int4 wlds[4 * CV];   // [q][CV][16B] = 32 KB
    const int c = blockIdx.y;
    const int4* wsrc = (const int4*)(wb + (size_t)c * 4 * CV * 8);
    for (int r = threadIdx.x; r < 4 * CV; r += 256) wlds[r] = wsrc[r];

    const int wid = threadIdx.x >> 6, lane = threadIdx.x & 63;
    const int q = lane >> 4, l15 = lane & 15;
    const int p0 = (blockIdx.x * 4 + wid) * PIXW;

    bf16x8 bfrag[TPW];
#pragma unroll
    for (int t = 0; t < TPW; ++t)
        bfrag[t] = *(const bf16x8*)(xb + ((size_t)q * P_TOT + p0 + t * 16 + l15) * 8);

    __syncthreads();

    f32x4 z = {0.f, 0.f, 0.f, 0.f};
    float run[TPW];
#pragma unroll
    for (int t = 0; t < TPW; ++t) run[t] = 3.0e38f;

    const short* wl = (const short*)wlds + (size_t)q * CV * 8;
#pragma unroll 2
    for (int s = 0; s < CV / 16; ++s) {
        bf16x8 a = *(const bf16x8*)(wl + (s * 16 + l15) * 8);   // ds_read_b128
        f32x4 acc[TPW];
#pragma unroll
        for (int t = 0; t < TPW; ++t)
            acc[t] = __builtin_amdgcn_mfma_f32_16x16x32_bf16(a, bfrag[t], z, 0, 0, 0);
#pragma unroll
        for (int t = 0; t < TPW; ++t) {
            float m = fminf(fminf(acc[t][0], acc[t][1]), acc[t][2]);   // v_min3
            m = fminf(m, acc[t][3]);
            run[t] = fminf(run[t], m);
        }
    }
#pragma unroll
    for (int t = 0; t < TPW; ++t) {
        float v = run[t];
        v = fminf(v, __shfl_xor(v, 16, 64));
        v = fminf(v, __shfl_xor(v, 32, 64));
        if (lane < 16)
            chunkmin[(size_t)c * P_TOT + p0 + t * 16 + lane] = v;
    }
}

// ---------------- pass B: exact fp32 refine over candidate chunks ----------
__global__ __launch_bounds__(256)
void pass_b(const float* __restrict__ chunkmin, const float* __restrict__ xn,
            const unsigned* __restrict__ n2max, const float* __restrict__ c2buf,
            const float* __restrict__ feats, const float* __restrict__ ve,
            unsigned long long* __restrict__ keys)
{
    __shared__ float cmins[NCH][64];
    __shared__ float Tsh[64];
    __shared__ float xlds[16][64];               // holds -2*x
    __shared__ unsigned long long candm[NCH];
    const int p0 = blockIdx.x * 64;
    const int tid = threadIdx.x;

    for (int i = tid; i < NCH * 64; i += 256) {
        int c = i >> 6, t = i & 63;
        cmins[c][t] = chunkmin[(size_t)c * P_TOT + p0 + t];
    }
    for (int i = tid; i < 16 * 64; i += 256) {
        int k = i >> 6, t = i & 63;
        int p = p0 + t, b = p / HW, hw = p - b * HW;
        xlds[k][t] = -2.f * feats[((size_t)b * DIMS + k) * HW + hw];
    }
    __syncthreads();

    if (tid < 64) {
        float gm = 3.0e38f;
        for (int c = 0; c < NCH; ++c) gm = fminf(gm, cmins[c][tid]);
        float Wm = sqrtf(__uint_as_float(*n2max));
        float mp = 0.004f * xn[p0 + tid] * Wm + 1e-3f;
        Tsh[tid] = gm + 2.f * mp;
    }
    __syncthreads();

    if (tid < 64) {     // wave 0 builds per-chunk candidate pixel masks
        for (int c = 0; c < NCH; ++c) {
            unsigned long long m = __ballot(cmins[c][tid] <= Tsh[tid]);
            if (tid == 0) candm[c] = m;
        }
    }
    __syncthreads();

    for (int c = 0; c < NCH; ++c) {
        unsigned long long m = candm[c];
        while (m) {
            int t = __ffsll((unsigned long long)m) - 1;
            m &= m - 1;
            unsigned long long best = ~0ull;
            int vend = min((c + 1) * CV, V_TOT);
            for (int v = c * CV + tid; v < vend; v += 256) {
                const float4* w4 = (const float4*)(ve + (size_t)v * DIMS);
                float4 a = w4[0], b4 = w4[1], cc = w4[2], d4 = w4[3];
                float s = c2buf[v];
                s = fmaf(xlds[0][t],  a.x,  s); s = fmaf(xlds[1][t],  a.y,  s);
                s = fmaf(xlds[2][t],  a.z,  s); s = fmaf(xlds[3][t],  a.w,  s);
                s = fmaf(xlds[4][t],  b4.x, s); s = fmaf(xlds[5][t],  b4.y, s);
                s = fmaf(xlds[6][t],  b4.z, s); s = fmaf(xlds[7][t],  b4.w, s);
                s = fmaf(xlds[8][t],  cc.x, s); s = fmaf(xlds[9][t],  cc.y, s);
                s = fmaf(xlds[10][t], cc.z, s); s = fmaf(xlds[11][t], cc.w, s);
                s = fmaf(xlds[12][t], d4.x, s); s = fmaf(xlds[13][t], d4.y, s);
                s = fmaf(xlds[14][t], d4.z, s); s = fmaf(xlds[15][t], d4.w, s);
                unsigned long long key =
                    ((unsigned long long)sortable(s) << 32) | (unsigned)v;
                best = (key < best) ? key : best;
            }
            for (int off = 32; off; off >>= 1) {
                unsigned long long o = __shfl_xor(best, off, 64);
                best = (o < best) ? o : best;
            }
            if ((tid & 63) == 0) atomicMin(&keys[p0 + t], best);
        }
    }
}

__global__ void cse_finalize(const unsigned long long* __restrict__ keys,
                             float* __restrict__ out)
{
    int p = blockIdx.x * 256 + threadIdx.x;
    if (p < P_TOT)
        out[FEAT_N + p] = (float)(unsigned)(keys[p] & 0xffffffffull);
}

// ---------------- fallback (round-1 proven VALU kernel) --------------------
__global__ __launch_bounds__(256, 2)
void cse_argmin(const float* __restrict__ feats, const float* __restrict__ ve,
                unsigned long long* __restrict__ keys)
{
    __shared__ float4 se4[VC * 4];
    __shared__ float  sh[VC];
    const int j = blockIdx.y, v0 = j * VC;
    const int cnt = min(VC, V_TOT - v0);
    for (int t = threadIdx.x; t < cnt; t += 256) {
        const float4* w4 = (const float4*)(ve + (size_t)(v0 + t) * DIMS);
        float4 a = w4[0], b = w4[1], c = w4[2], d = w4[3];
        float h = a.x*a.x + a.y*a.y + a.z*a.z + a.w*a.w
                + b.x*b.x + b.y*b.y + b.z*b.z + b.w*b.w
                + c.x*c.x + c.y*c.y + c.z*c.z + c.w*c.w
                + d.x*d.x + d.y*d.y + d.z*d.z + d.w*d.w;
        se4[t*4+0] = make_float4(-a.x,-a.y,-a.z,-a.w);
        se4[t*4+1] = make_float4(-b.x,-b.y,-b.z,-b.w);
        se4[t*4+2] = make_float4(-c.x,-c.y,-c.z,-c.w);
        se4[t*4+3] = make_float4(-d.x,-d.y,-d.z,-d.w);
        sh[t] = 0.5f * h;
    }
    __syncthreads();
    const int p0 = (blockIdx.x * 256 + threadIdx.x) * PPT;
    const int bb = p0 / HW, hw = p0 - bb * HW;
    const float* fb = feats + (size_t)bb * (DIMS * HW) + hw;
    float4 x[DIMS];
#pragma unroll
    for (int d = 0; d < DIMS; ++d) x[d] = *(const float4*)(fb + d * HW);
    float m0b = 3.4e38f, m1b = 3.4e38f, m2b = 3.4e38f, m3b = 3.4e38f;
    int i0 = 0, i1 = 0, i2 = 0, i3 = 0;
#pragma unroll 2
    for (int v = 0; v < cnt; ++v) {
        const float h = sh[v];
        float m0 = h, m1 = h, m2 = h, m3 = h;
#pragma unroll
        for (int k = 0; k < 4; ++k) {
            const float4 nw = se4[v*4 + k];
            const float4 xa = x[4*k+0], xb = x[4*k+1], xc = x[4*k+2], xd = x[4*k+3];
            m0 = fmaf(nw.x, xa.x, m0); m0 = fmaf(nw.y, xb.x, m0);
            m0 = fmaf(nw.z, xc.x, m0); m0 = fmaf(nw.w, xd.x, m0);
            m1 = fmaf(nw.x, xa.y, m1); m1 = fmaf(nw.y, xb.y, m1);
            m1 = fmaf(nw.z, xc.y, m1); m1 = fmaf(nw.w, xd.y, m1);
            m2 = fmaf(nw.x, xa.z, m2); m2 = fmaf(nw.y, xb.z, m2);
            m2 = fmaf(nw.z, xc.z, m2); m2 = fmaf(nw.w, xd.z, m2);
            m3 = fmaf(nw.x, xa.w, m3); m3 = fmaf(nw.y, xb.w, m3);
            m3 = fmaf(nw.z, xc.w, m3); m3 = fmaf(nw.w, xd.w, m3);
        }
        const int vg = v0 + v;
        bool c0 = m0 < m0b; m0b = c0 ? m0 : m0b; i0 = c0 ? vg : i0;
        bool c1 = m1 < m1b; m1b = c1 ? m1 : m1b; i1 = c1 ? vg : i1;
        bool c2 = m2 < m2b; m2b = c2 ? m2 : m2b; i2 = c2 ? vg : i2;
        bool c3 = m3 < m3b; m3b = c3 ? m3 : m3b; i3 = c3 ? vg : i3;
    }
    unsigned long long* kp = keys + p0;
    float mb[PPT] = { m0b, m1b, m2b, m3b };
    int   ib[PPT] = { i0, i1, i2, i3 };
#pragma unroll
    for (int p = 0; p < PPT; ++p) {
        unsigned long long key = ((unsigned long long)sortable(mb[p]) << 32) | (unsigned)ib[p];
        atomicMin(&kp[p], key);
    }
}

extern "C" void kernel_launch(void* const* d_in, const int* in_sizes, int n_in,
                              void* d_out, int out_size, void* d_ws, size_t ws_size,
                              hipStream_t stream)
{
    const float* feats = (const float*)d_in[0];
    const float* ve    = (const float*)d_in[1];
    float* out = (float*)d_out;

    hipMemcpyAsync(out, feats, (size_t)FEAT_N * sizeof(float),
                   hipMemcpyDeviceToDevice, stream);

    if (ws_size >= WS_NEED) {
        char* ws = (char*)d_ws;
        unsigned long long* keys = (unsigned long long*)(ws + OFF_KEYS);
        unsigned* n2max   = (unsigned*)(ws + OFF_N2MAX);
        float*    c2buf   = (float*)(ws + OFF_C2);
        float*    xnorm   = (float*)(ws + OFF_XN);
        short*    xbuf    = (short*)(ws + OFF_XB);
        short*    wbuf    = (short*)(ws + OFF_WB);
        float*    cmin    = (float*)(ws + OFF_CM);

        hipMemsetAsync(keys, 0xFF, (size_t)P_TOT * 8, stream);
        hipMemsetAsync(n2max, 0, 4, stream);

        prep_v<<<VPAD / 256, 256, 0, stream>>>(ve, wbuf, c2buf, n2max);
        prep_x<<<P_TOT / 256, 256, 0, stream>>>(feats, xbuf, xnorm);
        pass_a<<<dim3(P_TOT / (4 * PIXW), NCH), 256, 0, stream>>>(xbuf, wbuf, cmin);
        pass_b<<<P_TOT / 64, 256, 0, stream>>>(cmin, xnorm, n2max, c2buf,
                                               feats, ve, keys);
        cse_finalize<<<(P_TOT + 255) / 256, 256, 0, stream>>>(keys, out);
    } else {
        unsigned long long* keys = (unsigned long long*)d_ws;
        hipMemsetAsync(d_ws, 0xFF, (size_t)P_TOT * 8, stream);
        cse_argmin<<<dim3(P_TOT / (256 * PPT), NV), 256, 0, stream>>>(feats, ve, keys);
        cse_finalize<<<(P_TOT + 255) / 256, 256, 0, stream>>>(keys, out);
    }
}